// Round 7
// baseline (49.552 us; speedup 1.0000x reference)
//
#include <hip/hip_runtime.h>

#define IN_F  1024
#define HID_F 1024
#define OUT_F 512
#define BATCH 128
#define IC    32          // i-chunks for layer 1
#define CI    (IN_F/IC)   // 32 i per chunk

__device__ __forceinline__ float sigm(float v) { return 1.0f / (1.0f + __expf(-v)); }

// kT: blocks [0,512): w2s = sigm(w2); blocks [512,640): transpose x -> xt[1024][128]
__global__ __launch_bounds__(256) void kT(const float* __restrict__ x,
                                          const float* __restrict__ w2,
                                          float* __restrict__ xt,
                                          float* __restrict__ w2s) {
    const int bx = blockIdx.x, tid = threadIdx.x;
    if (bx < 512) {
        const int e = (bx * 256 + tid) * 4;
        const float4 v = *(const float4*)(w2 + e);
        float4 r;
        r.x = sigm(v.x); r.y = sigm(v.y); r.z = sigm(v.z); r.w = sigm(v.w);
        *(float4*)(w2s + e) = r;
    } else {
        __shared__ float tile[32][33];
        const int bt = bx - 512;
        const int i0 = (bt & 31) * 32, b0 = (bt >> 5) * 32;
        const int tx = tid & 31, ty = tid >> 5;   // ty 0..7
#pragma unroll
        for (int r = 0; r < 32; r += 8)
            tile[ty + r][tx] = x[(size_t)(b0 + ty + r) * IN_F + i0 + tx];
        __syncthreads();
#pragma unroll
        for (int r = 0; r < 32; r += 8)
            xt[(size_t)(i0 + ty + r) * BATCH + b0 + tx] = tile[tx][ty + r];
    }
}

// k1: layer-1 partials. grid (16 j-tiles, 32 i-chunks) = 512 blocks x 512 thr.
// Each block: j-tile 64 (lanes), ALL 128 b (8 waves x acc[16]), i-chunk 32.
// Sigmoids computed once per (i,j) into LDS: acs[i][j*2]={A,C}, A=1-w*s, C=w*(2s-1).
// x read via wave-uniform address (readfirstlane) -> s_load_dwordx16 -> SGPR
// operand in FMA: inner loop has ONE ds_read_b64 per 32 VALU ops.
__global__ __launch_bounds__(512, 4) void k1(const float* __restrict__ w1,
                                             const float* __restrict__ s1,
                                             const float* __restrict__ xt,
                                             float* __restrict__ P) {
    __shared__ float acs[CI][128];     // [32][64j x {A,C}] = 16 KB
    const int tid  = threadIdx.x;
    const int lane = tid & 63;
    const int wvu  = __builtin_amdgcn_readfirstlane(tid >> 6);  // provably scalar
    const int j0 = blockIdx.x * 64, i0 = blockIdx.y * CI;

    // stage: sigmoid(w1,s1) -> (A,C) pairs. thread t: i = t>>4, 4 j at (t&15)*4
    {
        const int i = tid >> 4, jq = (tid & 15) * 4;
        const float4 wq = *(const float4*)(w1 + (size_t)(i0 + i) * HID_F + j0 + jq);
        const float4 sq = *(const float4*)(s1 + (size_t)(i0 + i) * HID_F + j0 + jq);
        float4 lo, hi;
        float w_ = sigm(wq.x), s_ = sigm(sq.x);
        lo.x = 1.0f - w_ * s_; lo.y = w_ * (2.0f * s_ - 1.0f);
        w_ = sigm(wq.y); s_ = sigm(sq.y);
        lo.z = 1.0f - w_ * s_; lo.w = w_ * (2.0f * s_ - 1.0f);
        w_ = sigm(wq.z); s_ = sigm(sq.z);
        hi.x = 1.0f - w_ * s_; hi.y = w_ * (2.0f * s_ - 1.0f);
        w_ = sigm(wq.w); s_ = sigm(sq.w);
        hi.z = 1.0f - w_ * s_; hi.w = w_ * (2.0f * s_ - 1.0f);
        *(float4*)&acs[i][jq * 2]     = lo;
        *(float4*)&acs[i][jq * 2 + 4] = hi;
    }
    __syncthreads();

    float acc[16];
#pragma unroll
    for (int k = 0; k < 16; ++k) acc[k] = 1.0f;
    const int b0w = wvu * 16;
    const float* __restrict__ xrow = xt + (size_t)i0 * BATCH + b0w;  // scalar addr

#pragma unroll 4
    for (int ii = 0; ii < CI; ++ii) {
        const float2 ac = *(const float2*)&acs[ii][lane * 2];  // 512B contig, free
        const float* __restrict__ xp = xrow + ii * BATCH;      // uniform -> s_load
#pragma unroll
        for (int k = 0; k < 16; ++k)
            acc[k] *= fmaf(xp[k], ac.y, ac.x);                 // SGPR x-operand
    }
    float* Pp = P + ((size_t)blockIdx.y * BATCH + b0w) * HID_F + j0 + lane;
#pragma unroll
    for (int k = 0; k < 16; ++k)
        Pp[(size_t)k * HID_F] = acc[k];                        // coalesced 256B
}

// k2: combine IC chunks -> h (LDS, b-major) + layer 2. grid (8 o, 32 b4) = 256 x 512.
// Inner: per 4 j: four uniform ds_read_b128 (one per b) + 16 FMA; w2s 16-deep
// register double-buffer prefetch.
__global__ __launch_bounds__(512, 4) void k2(const float* __restrict__ w2s,
                                             const float* __restrict__ P,
                                             float* __restrict__ out) {
    __shared__ float hs[4][HID_F];     // 16 KB
    __shared__ float ps[8][64][4];     // 8 KB
    const int tid = threadIdx.x, lane = tid & 63, wv = tid >> 6;
    const int o0 = blockIdx.x * 64, b0 = blockIdx.y * 4;

    // h-stage: thread t: b = t>>7, 8 j at (t&127)*8; product over IC chunks
    {
        const int b = tid >> 7, jb = (tid & 127) * 8;
        float4 m0 = make_float4(1, 1, 1, 1), m1 = make_float4(1, 1, 1, 1);
#pragma unroll 8
        for (int c = 0; c < IC; ++c) {
            const float* p = P + ((size_t)c * BATCH + b0 + b) * HID_F + jb;
            const float4 a = *(const float4*)p, q = *(const float4*)(p + 4);
            m0.x *= a.x; m0.y *= a.y; m0.z *= a.z; m0.w *= a.w;
            m1.x *= q.x; m1.y *= q.y; m1.z *= q.z; m1.w *= q.w;
        }
        *(float4*)&hs[b][jb] = m0; *(float4*)&hs[b][jb + 4] = m1;
    }
    __syncthreads();

    float acc[4] = {1.0f, 1.0f, 1.0f, 1.0f};
    const float* wp = w2s + (size_t)(wv * 128) * OUT_F + o0 + lane;
    const int jbase = wv * 128;
    float wb[2][16];
#pragma unroll
    for (int jj = 0; jj < 16; ++jj) wb[0][jj] = wp[(size_t)jj * OUT_F];
#pragma unroll
    for (int blk = 0; blk < 8; ++blk) {
        if (blk < 7) {
#pragma unroll
            for (int jj = 0; jj < 16; ++jj)
                wb[(blk + 1) & 1][jj] = wp[(size_t)((blk + 1) * 16 + jj) * OUT_F];
        }
#pragma unroll
        for (int g = 0; g < 4; ++g) {
            const int j = jbase + blk * 16 + g * 4;
            const float4 h0 = *(const float4*)&hs[0][j];   // uniform b128 broadcast
            const float4 h1 = *(const float4*)&hs[1][j];
            const float4 h2 = *(const float4*)&hs[2][j];
            const float4 h3 = *(const float4*)&hs[3][j];
            float w;
            w = wb[blk & 1][g * 4 + 0];
            acc[0] *= fmaf(-w, h0.x, 1.0f); acc[1] *= fmaf(-w, h1.x, 1.0f);
            acc[2] *= fmaf(-w, h2.x, 1.0f); acc[3] *= fmaf(-w, h3.x, 1.0f);
            w = wb[blk & 1][g * 4 + 1];
            acc[0] *= fmaf(-w, h0.y, 1.0f); acc[1] *= fmaf(-w, h1.y, 1.0f);
            acc[2] *= fmaf(-w, h2.y, 1.0f); acc[3] *= fmaf(-w, h3.y, 1.0f);
            w = wb[blk & 1][g * 4 + 2];
            acc[0] *= fmaf(-w, h0.z, 1.0f); acc[1] *= fmaf(-w, h1.z, 1.0f);
            acc[2] *= fmaf(-w, h2.z, 1.0f); acc[3] *= fmaf(-w, h3.z, 1.0f);
            w = wb[blk & 1][g * 4 + 3];
            acc[0] *= fmaf(-w, h0.w, 1.0f); acc[1] *= fmaf(-w, h1.w, 1.0f);
            acc[2] *= fmaf(-w, h2.w, 1.0f); acc[3] *= fmaf(-w, h3.w, 1.0f);
        }
    }
    *(float4*)&ps[wv][lane][0] = make_float4(acc[0], acc[1], acc[2], acc[3]);
    __syncthreads();
    if (tid < 256) {
        const int o = tid & 63, b = tid >> 6;
        float pr = 1.0f;
#pragma unroll
        for (int w = 0; w < 8; ++w) pr *= ps[w][o][b];
        out[(size_t)(b0 + b) * OUT_F + o0 + o] = 1.0f - pr;
    }
}

extern "C" void kernel_launch(void* const* d_in, const int* in_sizes, int n_in,
                              void* d_out, int out_size, void* d_ws, size_t ws_size,
                              hipStream_t stream) {
    const float* x  = (const float*)d_in[0];
    const float* w1 = (const float*)d_in[1];
    const float* s1 = (const float*)d_in[2];
    const float* w2 = (const float*)d_in[3];
    float* out = (float*)d_out;

    // ws layout (floats): xt 512KB | w2s 2MB | P 16MB
    float* xt  = (float*)d_ws;
    float* w2s = xt + (size_t)IN_F * BATCH;
    float* P   = w2s + (size_t)HID_F * OUT_F;

    kT<<<640, 256, 0, stream>>>(x, w2, xt, w2s);
    k1<<<dim3(HID_F / 64, IC), 512, 0, stream>>>(w1, s1, xt, P);
    k2<<<dim3(OUT_F / 64, BATCH / 4), 512, 0, stream>>>(w2s, P, out);
}

// Round 8
// 47.108 us; speedup vs baseline: 1.0519x; 1.0519x over previous
//
#include <hip/hip_runtime.h>

#define IN_F  1024
#define HID_F 1024
#define OUT_F 512
#define BATCH 128
#define IC1   32   // i-chunks layer 1 (32 i each)
#define JC2   32   // j-chunks layer 2 (32 j each)

__device__ __forceinline__ float sigm(float v) { return 1.0f / (1.0f + __expf(-v)); }

__device__ __forceinline__ float rdlane(float v, int l) {
    return __int_as_float(__builtin_amdgcn_readlane(__float_as_int(v), l));
}

// kPre: [0,1024): AC[(i*1024+j)*2]={A,C}, A=1-w*s, C=w*(2s-1)
//       [1024,1536): w2s = sigm(w2);  [1536,1664): x -> xt[1024][128]
__global__ __launch_bounds__(256) void kPre(const float* __restrict__ x,
                                            const float* __restrict__ w1,
                                            const float* __restrict__ s1,
                                            const float* __restrict__ w2,
                                            float* __restrict__ xt,
                                            float* __restrict__ AC,
                                            float* __restrict__ w2s) {
    const int bx = blockIdx.x, tid = threadIdx.x;
    if (bx < 1024) {
        const int e = (bx * 256 + tid) * 4;
        const float4 wv = *(const float4*)(w1 + e);
        const float4 sv = *(const float4*)(s1 + e);
        float4 lo, hi;
        float w_ = sigm(wv.x), s_ = sigm(sv.x);
        lo.x = 1.0f - w_ * s_; lo.y = w_ * (2.0f * s_ - 1.0f);
        w_ = sigm(wv.y); s_ = sigm(sv.y);
        lo.z = 1.0f - w_ * s_; lo.w = w_ * (2.0f * s_ - 1.0f);
        w_ = sigm(wv.z); s_ = sigm(sv.z);
        hi.x = 1.0f - w_ * s_; hi.y = w_ * (2.0f * s_ - 1.0f);
        w_ = sigm(wv.w); s_ = sigm(sv.w);
        hi.z = 1.0f - w_ * s_; hi.w = w_ * (2.0f * s_ - 1.0f);
        *(float4*)(AC + (size_t)2 * e)     = lo;
        *(float4*)(AC + (size_t)2 * e + 4) = hi;
    } else if (bx < 1536) {
        const int e = ((bx - 1024) * 256 + tid) * 4;
        const float4 wv = *(const float4*)(w2 + e);
        float4 r;
        r.x = sigm(wv.x); r.y = sigm(wv.y); r.z = sigm(wv.z); r.w = sigm(wv.w);
        *(float4*)(w2s + e) = r;
    } else {
        __shared__ float tile[32][33];
        const int bt = bx - 1536;
        const int i0 = (bt & 31) * 32, b0 = (bt >> 5) * 32;
        const int tx = tid & 31, ty = tid >> 5;
#pragma unroll
        for (int r = 0; r < 32; r += 8)
            tile[ty + r][tx] = x[(size_t)(b0 + ty + r) * IN_F + i0 + tx];
        __syncthreads();
#pragma unroll
        for (int r = 0; r < 32; r += 8)
            xt[(size_t)(i0 + ty + r) * BATCH + b0 + tx] = tile[tx][ty + r];
    }
}

// k1: layer-1 partials. grid (16 j-tiles, 32 i-chunks), 512 thr (8 waves).
// Wave w: b-slice 16 at w*16; lanes span 64 j. x-slice held per-lane
// (lane 2i: b 0..7, lane 2i+1: b 8..15) and broadcast via v_readlane (no LDS).
// AC streamed as coalesced per-lane b64 global loads.
__global__ __launch_bounds__(512, 4) void k1(const float* __restrict__ AC,
                                             const float* __restrict__ xt,
                                             float* __restrict__ P) {
    const int tid = threadIdx.x, lane = tid & 63, wv = tid >> 6;
    const int j0 = blockIdx.x * 64, i0 = blockIdx.y * 32;
    const int b0w = wv * 16;

    // per-lane x tile: xr[k] = xt[i0 + (lane>>1)][b0w + (lane&1)*8 + k]
    float xr[8];
    {
        const float* s = xt + (size_t)(i0 + (lane >> 1)) * BATCH + b0w + (lane & 1) * 8;
        const float4 a = *(const float4*)s, b = *(const float4*)(s + 4);
        xr[0] = a.x; xr[1] = a.y; xr[2] = a.z; xr[3] = a.w;
        xr[4] = b.x; xr[5] = b.y; xr[6] = b.z; xr[7] = b.w;
    }

    float acc[16];
#pragma unroll
    for (int k = 0; k < 16; ++k) acc[k] = 1.0f;

    const float* acp = AC + ((size_t)i0 * HID_F + j0 + lane) * 2;
    for (int g = 0; g < 8; ++g) {            // 8 groups x 4 i
        float2 ac[4];
#pragma unroll
        for (int u = 0; u < 4; ++u)
            ac[u] = *(const float2*)(acp + (size_t)(g * 4 + u) * (HID_F * 2));
#pragma unroll
        for (int u = 0; u < 4; ++u) {
            const int base = 8 * g + 2 * u;  // = 2*i (uniform)
#pragma unroll
            for (int k = 0; k < 8; ++k) {
                const float xa = rdlane(xr[k], base);      // b = b0w+k
                const float xb = rdlane(xr[k], base + 1);  // b = b0w+8+k
                acc[k]     *= fmaf(xa, ac[u].y, ac[u].x);
                acc[k + 8] *= fmaf(xb, ac[u].y, ac[u].x);
            }
        }
    }
    float* Pp = P + ((size_t)blockIdx.y * BATCH + b0w) * HID_F + j0 + lane;
#pragma unroll
    for (int m = 0; m < 16; ++m)
        Pp[(size_t)m * HID_F] = acc[m];      // coalesced 256B rows
}

// kC1: combine 32 P-chunks -> ht[j][b]. grid 256 x 512 thr.
__global__ __launch_bounds__(512, 4) void kC1(const float* __restrict__ P,
                                              float* __restrict__ ht) {
    const int tid = threadIdx.x;
    const int j = (blockIdx.x & 7) * 128 + (tid & 127);
    const int b = (blockIdx.x >> 3) * 4 + (tid >> 7);
    float p0 = 1.0f, p1 = 1.0f;
#pragma unroll 8
    for (int c = 0; c < IC1; c += 2) {
        p0 *= P[((size_t)c * BATCH + b) * HID_F + j];
        p1 *= P[((size_t)(c + 1) * BATCH + b) * HID_F + j];
    }
    ht[(size_t)j * BATCH + b] = p0 * p1;
}

// k2: layer-2 partials. grid (8 o-tiles, 32 j-chunks), 512 thr.
// Same register-broadcast trick for h; w2s per-lane coalesced b32.
__global__ __launch_bounds__(512, 4) void k2(const float* __restrict__ w2s,
                                             const float* __restrict__ ht,
                                             float* __restrict__ Q) {
    const int tid = threadIdx.x, lane = tid & 63, wv = tid >> 6;
    const int o0 = blockIdx.x * 64, j0 = blockIdx.y * 32;
    const int b0w = wv * 16;

    float hr[8];
    {
        const float* s = ht + (size_t)(j0 + (lane >> 1)) * BATCH + b0w + (lane & 1) * 8;
        const float4 a = *(const float4*)s, b = *(const float4*)(s + 4);
        hr[0] = a.x; hr[1] = a.y; hr[2] = a.z; hr[3] = a.w;
        hr[4] = b.x; hr[5] = b.y; hr[6] = b.z; hr[7] = b.w;
    }

    float acc[16];
#pragma unroll
    for (int k = 0; k < 16; ++k) acc[k] = 1.0f;

    const float* wp = w2s + (size_t)j0 * OUT_F + o0 + lane;
    for (int g = 0; g < 8; ++g) {            // 8 groups x 4 j
        float w4[4];
#pragma unroll
        for (int u = 0; u < 4; ++u)
            w4[u] = wp[(size_t)(g * 4 + u) * OUT_F];
#pragma unroll
        for (int u = 0; u < 4; ++u) {
            const int base = 8 * g + 2 * u;
#pragma unroll
            for (int k = 0; k < 8; ++k) {
                const float ha = rdlane(hr[k], base);
                const float hb = rdlane(hr[k], base + 1);
                acc[k]     *= fmaf(-w4[u], ha, 1.0f);
                acc[k + 8] *= fmaf(-w4[u], hb, 1.0f);
            }
        }
    }
    float* Qp = Q + ((size_t)blockIdx.y * BATCH + b0w) * OUT_F + o0 + lane;
#pragma unroll
    for (int m = 0; m < 16; ++m)
        Qp[(size_t)m * OUT_F] = acc[m];
}

// kC2: out[b][o] = 1 - prod over JC2 chunks. 256 x 256 thr.
__global__ __launch_bounds__(256, 4) void kC2(const float* __restrict__ Q,
                                              float* __restrict__ out) {
    const int g = blockIdx.x * 256 + threadIdx.x;   // 65536 outputs
    float p0 = 1.0f, p1 = 1.0f;
#pragma unroll 8
    for (int c = 0; c < JC2; c += 2) {
        p0 *= Q[(size_t)c * (BATCH * OUT_F) + g];
        p1 *= Q[(size_t)(c + 1) * (BATCH * OUT_F) + g];
    }
    out[g] = 1.0f - p0 * p1;
}

extern "C" void kernel_launch(void* const* d_in, const int* in_sizes, int n_in,
                              void* d_out, int out_size, void* d_ws, size_t ws_size,
                              hipStream_t stream) {
    const float* x  = (const float*)d_in[0];
    const float* w1 = (const float*)d_in[1];
    const float* s1 = (const float*)d_in[2];
    const float* w2 = (const float*)d_in[3];
    float* out = (float*)d_out;

    // ws (floats): xt 512KB | w2s 2MB | AC 8MB | ht 512KB | P 16MB | Q 8MB
    float* xt  = (float*)d_ws;
    float* w2s = xt + (size_t)IN_F * BATCH;
    float* AC  = w2s + (size_t)HID_F * OUT_F;
    float* ht  = AC + (size_t)2 * IN_F * HID_F;
    float* P   = ht + (size_t)HID_F * BATCH;
    float* Q   = P + (size_t)IC1 * BATCH * HID_F;

    kPre<<<1664, 256, 0, stream>>>(x, w1, s1, w2, xt, AC, w2s);
    k1<<<dim3(HID_F / 64, IC1), 512, 0, stream>>>(AC, xt, P);
    kC1<<<256, 512, 0, stream>>>(P, ht);
    k2<<<dim3(OUT_F / 64, JC2), 512, 0, stream>>>(w2s, ht, Q);
    kC2<<<256, 256, 0, stream>>>(Q, out);
}

// Round 9
// 38.716 us; speedup vs baseline: 1.2799x; 1.2168x over previous
//
#include <hip/hip_runtime.h>

#define IN_F  1024
#define HID_F 1024
#define OUT_F 512
#define BATCH 128
#define IC    16   // layer-1 i-chunks (64 i each); P = IC*1024*128 floats
#define JC    32   // layer-2 j-chunks (32 j each); Q = JC*512*128 floats

__device__ __forceinline__ float sigm(float v) { return 1.0f / (1.0f + __expf(-v)); }

typedef __attribute__((ext_vector_type(8))) float f32x8;

// Scalar-pipe broadcast load: 8 consecutive floats at a wave-uniform address
// into SGPRs. Consumer must call swait before reading (SMEM is out-of-order,
// so waits are lgkmcnt(0) batched). Data-dependency through the tied "+s"
// operands orders the consumers after the wait.
__device__ __forceinline__ f32x8 sld8(const float* p, int off_bytes) {
    f32x8 r;
    asm volatile("s_load_dwordx8 %0, %1, %2"
                 : "=&s"(r) : "s"(p), "s"(off_bytes));
    return r;
}
__device__ __forceinline__ void swait4(f32x8& a, f32x8& b, f32x8& c, f32x8& d) {
    asm volatile("s_waitcnt lgkmcnt(0)"
                 : "+s"(a), "+s"(b), "+s"(c), "+s"(d));
}
__device__ __forceinline__ void swait1(f32x8& a) {
    asm volatile("s_waitcnt lgkmcnt(0)" : "+s"(a));
}

// kPre: S1 [0,256): per (i,j): w=sigm(w1), s=sigm(s1), A=1-ws, C=w(2s-1);
//                   D[i][j]=C/A; PA16[sc][j]=prod of A over 16-i subchunk.
//       S2 [256,768): w2s = sigm(w2)          (layout [j][o], o-contig)
//       S3 [768,896): transpose x -> xt[1024][128]
__global__ __launch_bounds__(256) void kPre(const float* __restrict__ x,
                                            const float* __restrict__ w1,
                                            const float* __restrict__ s1,
                                            const float* __restrict__ w2,
                                            float* __restrict__ xt,
                                            float* __restrict__ Dm,
                                            float* __restrict__ PA16,
                                            float* __restrict__ w2s) {
    const int bx = blockIdx.x, tid = threadIdx.x;
    if (bx < 256) {
        const int sc = bx >> 2;                 // 0..63 (16-i subchunk)
        const int j  = (bx & 3) * 256 + tid;    // 0..1023
        float pa = 1.0f;
#pragma unroll 4
        for (int ii = 0; ii < 16; ++ii) {
            const int i = sc * 16 + ii;
            const float w = sigm(w1[(size_t)i * HID_F + j]);
            const float s = sigm(s1[(size_t)i * HID_F + j]);
            const float A = 1.0f - w * s;
            const float C = w * (2.0f * s - 1.0f);
            Dm[(size_t)i * HID_F + j] = C / A;  // A in (0.61,0.86): safe
            pa *= A;
        }
        PA16[(size_t)sc * HID_F + j] = pa;
    } else if (bx < 768) {
        const int e = ((bx - 256) * 256 + tid) * 4;
        const float4 v = *(const float4*)(w2 + e);
        float4 r;
        r.x = sigm(v.x); r.y = sigm(v.y); r.z = sigm(v.z); r.w = sigm(v.w);
        *(float4*)(w2s + e) = r;
    } else {
        __shared__ float tile[32][33];
        const int bt = bx - 768;
        const int i0 = (bt & 31) * 32, b0 = (bt >> 5) * 32;
        const int tx = tid & 31, ty = tid >> 5;
#pragma unroll
        for (int r = 0; r < 32; r += 8)
            tile[ty + r][tx] = x[(size_t)(b0 + ty + r) * IN_F + i0 + tx];
        __syncthreads();
#pragma unroll
        for (int r = 0; r < 32; r += 8)
            xt[(size_t)(i0 + ty + r) * BATCH + b0 + tx] = tile[tx][ty + r];
    }
}

// k1: layer-1 partials. grid (16 j-grps of 64, 2 b-halves, IC chunks) x 512 thr.
// lanes = b (coalesced x loads); wave -> 8-j slice; D,PA16 arrive via s_load
// (SGPR broadcast, scalar pipe). Inner op: acc[jj] *= fmaf(x, D_s, 1) — 2 VALU.
// P[ic][j][b] = PA * prod(1 + x*D) = prod(A + x*C) over the chunk.
__global__ __launch_bounds__(512, 4) void k1(const float* __restrict__ Dm,
                                             const float* __restrict__ PA16,
                                             const float* __restrict__ xt,
                                             float* __restrict__ P) {
    const int tid  = threadIdx.x;
    const int lane = tid & 63;
    const int wvu  = __builtin_amdgcn_readfirstlane(tid >> 6);  // 0..7
    const int j0w  = blockIdx.x * 64 + wvu * 8;
    const int b    = blockIdx.y * 64 + lane;
    const int i0   = blockIdx.z * 64;

    float acc[8];
#pragma unroll
    for (int k = 0; k < 8; ++k) acc[k] = 1.0f;

    const float* xp = xt + (size_t)i0 * BATCH + b;      // per-lane, coalesced
    const int dbase = (i0 * HID_F + j0w) * 4;           // uniform byte offset

#pragma unroll 1
    for (int sc = 0; sc < 4; ++sc) {                    // 4 subchunks x 16 i
        f32x8 pa = sld8(PA16, ((blockIdx.z * 4 + sc) * HID_F + j0w) * 4);
#pragma unroll 1
        for (int bt = 0; bt < 4; ++bt) {                // 4 i per batch
            const int ib = sc * 16 + bt * 4;
            f32x8 d0 = sld8(Dm, dbase + (ib + 0) * (HID_F * 4));
            f32x8 d1 = sld8(Dm, dbase + (ib + 1) * (HID_F * 4));
            f32x8 d2 = sld8(Dm, dbase + (ib + 2) * (HID_F * 4));
            f32x8 d3 = sld8(Dm, dbase + (ib + 3) * (HID_F * 4));
            const float x0 = xp[(ib + 0) * BATCH];
            const float x1 = xp[(ib + 1) * BATCH];
            const float x2 = xp[(ib + 2) * BATCH];
            const float x3 = xp[(ib + 3) * BATCH];
            swait4(d0, d1, d2, d3);
#pragma unroll
            for (int jj = 0; jj < 8; ++jj) {
                acc[jj] *= fmaf(x0, d0[jj], 1.0f);
                acc[jj] *= fmaf(x1, d1[jj], 1.0f);
                acc[jj] *= fmaf(x2, d2[jj], 1.0f);
                acc[jj] *= fmaf(x3, d3[jj], 1.0f);
            }
        }
        swait1(pa);                                     // completed long ago
#pragma unroll
        for (int jj = 0; jj < 8; ++jj) acc[jj] *= pa[jj];
    }
#pragma unroll
    for (int jj = 0; jj < 8; ++jj)                      // coalesced 256B rows
        P[((size_t)blockIdx.z * HID_F + j0w + jj) * BATCH + b] = acc[jj];
}

// kC1: ht[j][b] = prod over IC chunks of P. All b-contig, fully coalesced.
__global__ __launch_bounds__(256) void kC1(const float* __restrict__ P,
                                           float* __restrict__ ht) {
    const int g = blockIdx.x * 256 + threadIdx.x;       // 131072
    const int j = g >> 7, b = g & 127;
    float p0 = 1.0f, p1 = 1.0f;
#pragma unroll
    for (int ic = 0; ic < IC; ic += 2) {
        p0 *= P[((size_t)ic * HID_F + j) * BATCH + b];
        p1 *= P[((size_t)(ic + 1) * HID_F + j) * BATCH + b];
    }
    ht[g] = p0 * p1;
}

// k2: layer-2 partials. grid (8 o-grps of 64, 2 b-halves, JC chunks) x 512 thr.
// lanes = b (coalesced ht loads); w2s via s_load broadcast.
// Q[jc][o][b] = prod over chunk of (1 - w2s*h).
__global__ __launch_bounds__(512, 4) void k2(const float* __restrict__ w2s,
                                             const float* __restrict__ ht,
                                             float* __restrict__ Q) {
    const int tid  = threadIdx.x;
    const int lane = tid & 63;
    const int wvu  = __builtin_amdgcn_readfirstlane(tid >> 6);
    const int o0w  = blockIdx.x * 64 + wvu * 8;
    const int b    = blockIdx.y * 64 + lane;
    const int j0   = blockIdx.z * 32;

    float acc[8];
#pragma unroll
    for (int k = 0; k < 8; ++k) acc[k] = 1.0f;

    const float* hp = ht + (size_t)j0 * BATCH + b;
    const int wbase = (j0 * OUT_F + o0w) * 4;

#pragma unroll 1
    for (int bt = 0; bt < 8; ++bt) {                    // 4 j per batch
        const int jb = bt * 4;
        f32x8 w0 = sld8(w2s, wbase + (jb + 0) * (OUT_F * 4));
        f32x8 w1 = sld8(w2s, wbase + (jb + 1) * (OUT_F * 4));
        f32x8 w2_ = sld8(w2s, wbase + (jb + 2) * (OUT_F * 4));
        f32x8 w3 = sld8(w2s, wbase + (jb + 3) * (OUT_F * 4));
        const float h0 = hp[(jb + 0) * BATCH];
        const float h1 = hp[(jb + 1) * BATCH];
        const float h2 = hp[(jb + 2) * BATCH];
        const float h3 = hp[(jb + 3) * BATCH];
        swait4(w0, w1, w2_, w3);
#pragma unroll
        for (int oo = 0; oo < 8; ++oo) {
            acc[oo] *= fmaf(-h0, w0[oo], 1.0f);
            acc[oo] *= fmaf(-h1, w1[oo], 1.0f);
            acc[oo] *= fmaf(-h2, w2_[oo], 1.0f);
            acc[oo] *= fmaf(-h3, w3[oo], 1.0f);
        }
    }
#pragma unroll
    for (int oo = 0; oo < 8; ++oo)                      // coalesced 256B rows
        Q[((size_t)blockIdx.z * OUT_F + o0w + oo) * BATCH + b] = acc[oo];
}

// kC2: out[b][o] = 1 - prod over JC chunks of Q; LDS micro-transpose so both
// the Q reads (b-lanes) and the out writes (o-minor segments) are coalesced.
__global__ __launch_bounds__(256) void kC2(const float* __restrict__ Q,
                                           float* __restrict__ out) {
    __shared__ float lds[8][132];
    const int tid = threadIdx.x;
    const int o0 = blockIdx.x * 8;                      // 64 blocks
    const int b = tid & 127, oi = tid >> 7;             // 0..1
#pragma unroll
    for (int r = 0; r < 4; ++r) {
        const int ol = oi * 4 + r;                      // 0..7
        float pr = 1.0f;
#pragma unroll 8
        for (int jc = 0; jc < JC; ++jc)
            pr *= Q[((size_t)jc * OUT_F + o0 + ol) * BATCH + b];
        lds[ol][b] = 1.0f - pr;
    }
    __syncthreads();
#pragma unroll
    for (int k = 0; k < 4; ++k) {
        const int ol = tid & 7, b2 = (tid >> 3) + k * 32;
        out[(size_t)b2 * OUT_F + o0 + ol] = lds[ol][b2];
    }
}

extern "C" void kernel_launch(void* const* d_in, const int* in_sizes, int n_in,
                              void* d_out, int out_size, void* d_ws, size_t ws_size,
                              hipStream_t stream) {
    const float* x  = (const float*)d_in[0];
    const float* w1 = (const float*)d_in[1];
    const float* s1 = (const float*)d_in[2];
    const float* w2 = (const float*)d_in[3];
    float* out = (float*)d_out;

    // ws layout (floats): D 4MB | PA16 256KB | w2s 2MB | xt 512KB | ht 512KB
    //                     | P 8MB | Q 8MB
    float* Dm   = (float*)d_ws;
    float* PA16 = Dm + (size_t)IN_F * HID_F;
    float* w2s  = PA16 + (size_t)64 * HID_F;
    float* xt   = w2s + (size_t)HID_F * OUT_F;
    float* ht   = xt + (size_t)IN_F * BATCH;
    float* P    = ht + (size_t)HID_F * BATCH;
    float* Q    = P + (size_t)IC * HID_F * BATCH;

    kPre<<<896, 256, 0, stream>>>(x, w1, s1, w2, xt, Dm, PA16, w2s);
    k1<<<dim3(16, 2, IC), 512, 0, stream>>>(Dm, PA16, xt, P);
    kC1<<<512, 256, 0, stream>>>(P, ht);
    k2<<<dim3(8, 2, JC), 512, 0, stream>>>(w2s, ht, Q);
    kC2<<<64, 256, 0, stream>>>(Q, out);
}